// Round 5
// baseline (323.867 us; speedup 1.0000x reference)
//
#include <hip/hip_runtime.h>
#include <hip/hip_bf16.h>
#include <stdint.h>

// Problem constants
constexpr int IN_DIM   = 2048;
constexpr int OUT_DIM  = 2048;
constexpr int BATCH    = 4096;
constexpr int KDIM     = 2 * IN_DIM;   // concatenated K: [xn | S] vs [scale_base | Wd]
constexpr float LN_EPS = 1e-5f;

#define TILE 128
#define BK   32
constexpr int NK     = KDIM / BK;      // 128 k-steps
constexpr int SLOT   = TILE * BK;      // shorts per matrix per slot (8 KB)
constexpr int NSLOT  = 3;              // ring depth (48 KB total LDS)

typedef __attribute__((ext_vector_type(8))) short  short8;  // 8 x bf16 (4 VGPRs)
typedef __attribute__((ext_vector_type(4))) float  f32x4;   // MFMA accumulator

__device__ __forceinline__ unsigned short f2bf(float f) {
  __hip_bfloat16 h = __float2bfloat16(f);
  return *reinterpret_cast<unsigned short*>(&h);
}
__device__ __forceinline__ unsigned pack2bf(float a, float b) {
  return (unsigned)f2bf(a) | ((unsigned)f2bf(b) << 16);
}

// ---------------------------------------------------------------------------
// Kernel 1: LayerNorm + RBF basis-sum. One block (256 thr) per batch row.
// Writes bf16 A = [xn | S] row-major (BATCH x KDIM).
// ---------------------------------------------------------------------------
__global__ __launch_bounds__(256) void ln_rbf_kernel(
    const float* __restrict__ x, const float* __restrict__ lnw,
    const float* __restrict__ lnb, const float* __restrict__ betap,
    const float* __restrict__ grid, unsigned short* __restrict__ A)
{
  const int row = blockIdx.x;
  const int tid = threadIdx.x;
  const float4* xr = reinterpret_cast<const float4*>(x + (size_t)row * IN_DIM);
  float4 v0 = xr[tid];
  float4 v1 = xr[tid + 256];
  float s = (v0.x + v0.y) + (v0.z + v0.w) + (v1.x + v1.y) + (v1.z + v1.w);
  float q = v0.x * v0.x + v0.y * v0.y + v0.z * v0.z + v0.w * v0.w
          + v1.x * v1.x + v1.y * v1.y + v1.z * v1.z + v1.w * v1.w;
  #pragma unroll
  for (int off = 32; off > 0; off >>= 1) {
    s += __shfl_down(s, off, 64);
    q += __shfl_down(q, off, 64);
  }
  __shared__ float red[10];
  const int lane = tid & 63, wv = tid >> 6;
  if (lane == 0) { red[wv] = s; red[4 + wv] = q; }
  __syncthreads();
  if (tid == 0) {
    float ts = (red[0] + red[1]) + (red[2] + red[3]);
    float tq = (red[4] + red[5]) + (red[6] + red[7]);
    float mu  = ts * (1.0f / IN_DIM);
    float var = tq * (1.0f / IN_DIM) - mu * mu;
    red[8] = mu;
    red[9] = rsqrtf(var + LN_EPS);
  }
  __syncthreads();
  const float mu = red[8], rs = red[9];
  const float beta = fminf(fmaxf(betap[0], 0.5f), 6.0f);
  float g[8];
  #pragma unroll
  for (int i = 0; i < 8; i++) g[i] = grid[i];
  const float4* w4 = reinterpret_cast<const float4*>(lnw);
  const float4* b4 = reinterpret_cast<const float4*>(lnb);
  unsigned short* Ar = A + (size_t)row * KDIM;
  #pragma unroll
  for (int h = 0; h < 2; h++) {
    const int idx = tid + h * 256;        // float4 index within the row
    float4 xv  = (h == 0) ? v0 : v1;
    float4 wv4 = w4[idx];
    float4 bv4 = b4[idx];
    float xa[4] = {xv.x, xv.y, xv.z, xv.w};
    float wa[4] = {wv4.x, wv4.y, wv4.z, wv4.w};
    float ba[4] = {bv4.x, bv4.y, bv4.z, bv4.w};
    float xn[4], S[4];
    #pragma unroll
    for (int c = 0; c < 4; c++) {
      float xnv = (xa[c] - mu) * rs * wa[c] + ba[c];
      xn[c] = xnv;
      float acc = 0.f;
      #pragma unroll
      for (int gg = 0; gg < 8; gg++) {
        float d = xnv - g[gg];
        acc += __expf(-beta * d * d);
      }
      S[c] = acc;
    }
    uint2 px, ps;
    px.x = pack2bf(xn[0], xn[1]);
    px.y = pack2bf(xn[2], xn[3]);
    ps.x = pack2bf(S[0], S[1]);
    ps.y = pack2bf(S[2], S[3]);
    *reinterpret_cast<uint2*>(Ar + idx * 4) = px;
    *reinterpret_cast<uint2*>(Ar + IN_DIM + idx * 4) = ps;
  }
}

// ---------------------------------------------------------------------------
// Kernel 2: pack bf16 B = [scale_base | Wd], Wd[o,i] = sum_g spline_weight.
// Fully-coalesced: one float4 per lane, shfl_xor/shfl_down g-reduction.
// ---------------------------------------------------------------------------
constexpr int SW_F4   = OUT_DIM * IN_DIM * 2;   // float4 count of spline_weight
constexpr int SB_F4   = OUT_DIM * IN_DIM / 4;   // float4 count of scale_base

__global__ __launch_bounds__(256) void pack_b_kernel(
    const float* __restrict__ sw, const float* __restrict__ sb,
    unsigned* __restrict__ Bu)    // B as uint (2 bf16 per uint), OUT x KDIM/2
{
  const int g = blockIdx.x * 256 + threadIdx.x;
  const int lane = threadIdx.x & 63;
  if (g < SW_F4) {
    float4 v = reinterpret_cast<const float4*>(sw)[g];
    float s = (v.x + v.y) + (v.z + v.w);
    s += __shfl_xor(s, 1, 64);                 // full Wd[i] in both lanes of pair
    float hi = __shfl_down(s, 2, 64);          // Wd of i+1 for even-pair lanes
    if ((lane & 3) == 0) {
      const int i_lin = g >> 1;                // linear (o,i)
      const int o = i_lin >> 11;               // / IN_DIM
      const int i = i_lin & (IN_DIM - 1);
      Bu[(size_t)o * (KDIM / 2) + (IN_DIM / 2) + (i >> 1)] = pack2bf(s, hi);
    }
  } else {
    const int t = g - SW_F4;                   // [0, SB_F4)
    float4 v = reinterpret_cast<const float4*>(sb)[t];
    const int o  = t >> 9;                     // 512 float4 per sb row
    const int i4 = t & 511;
    uint2 u;
    u.x = pack2bf(v.x, v.y);
    u.y = pack2bf(v.z, v.w);
    *reinterpret_cast<uint2*>(&Bu[(size_t)o * (KDIM / 2) + i4 * 2]) = u;
  }
}

// ---------------------------------------------------------------------------
// Kernel 3: C = A @ B^T + bias. Producer-consumer, DEEP-PIPELINED.
// 512 thr = 8 waves: waves 0-3 consumers (2x2 of 64x64, 4x4 MFMA accs),
// waves 4-7 producers. BK=32, 3-slot LDS ring (48 KB -> 2 blocks/CU).
// AITER-style fine vmcnt: producer issues stage kt (4 gld_lds16), then waits
// vmcnt(4) — stage kt-1's loads done, kt's still in flight — and signals
// kt-1 with a RELAXED ds-atomic (release would re-insert the vmcnt(0) drain).
// Steady state: 2 stages of loads permanently outstanding per producer wave.
// LDS layout: paired-row XOR swizzle — rows 2r,2r+1 share a 128-B line;
// 16-B granule gi = (row&1)*4 + kgran stored at gi ^ (line&7). Per-16-lane
// phase each bank is hit exactly 2x (free, m136). Swizzle folded into the
// producer's GLOBAL addresses (gld_lds dest is base+lane*16 [m104/m108]).
// ---------------------------------------------------------------------------
__device__ __forceinline__ void gld_lds16(const unsigned short* g, unsigned short* l) {
  __builtin_amdgcn_global_load_lds(
      (const __attribute__((address_space(1))) void*)g,
      (__attribute__((address_space(3))) void*)l, 16, 0, 0);
}

__global__ __launch_bounds__(512) void gemm_kernel(
    const unsigned short* __restrict__ A, const unsigned short* __restrict__ Bm,
    const float* __restrict__ bias, float* __restrict__ out)
{
  __shared__ __align__(16) unsigned short As[NSLOT * SLOT];   // 24 KB
  __shared__ __align__(16) unsigned short Bs[NSLOT * SLOT];   // 24 KB
  __shared__ unsigned prod_done, cons_done;

  const int tid  = threadIdx.x;
  const int lane = tid & 63;
  const int wv   = tid >> 6;       // 0..7
  const int m0   = blockIdx.y * TILE;
  const int n0   = blockIdx.x * TILE;

  if (tid == 0) { prod_done = 0u; cons_done = 0u; }
  __syncthreads();                 // flags visible; the ONLY block barrier

  if (wv >= 4) {
    // ----------------------- PRODUCER (waves 4-7) -----------------------
    const int p = wv - 4;
    // 512 16-B segs per matrix per stage; wave p owns segs [(2p+j)*64, +64).
    const unsigned short* Ap[2];
    const unsigned short* Bp[2];
    unsigned aBase[2], bBase[2];   // wave-uniform LDS short offsets (slot 0)
    #pragma unroll
    for (int j = 0; j < 2; j++) {
      const int seg  = (p * 2 + j) * 64 + lane;
      const int line = seg >> 3;                  // 128-B line (row pair)
      const int gi   = (seg & 7) ^ (line & 7);    // unswizzled granule
      const int row  = line * 2 + (gi >> 2);
      const int kg   = gi & 3;                    // 16-B k-granule within row
      Ap[j] = A  + (size_t)(m0 + row) * KDIM + kg * 8;
      Bp[j] = Bm + (size_t)(n0 + row) * KDIM + kg * 8;
      aBase[j] = (unsigned)((p * 2 + j) * 512);   // 64 segs * 8 shorts
      bBase[j] = aBase[j];
    }
    unsigned cdone = 0;
    #pragma unroll 1
    for (int kt = 0; kt < NK; kt++) {
      if (kt >= NSLOT) {           // slot reuse: stage kt-NSLOT fully consumed
        const unsigned need = 4u * (unsigned)(kt - NSLOT + 1);
        while (cdone < need) {
          cdone = __hip_atomic_load(&cons_done, __ATOMIC_RELAXED,
                                    __HIP_MEMORY_SCOPE_WORKGROUP);
          if (cdone < need) __builtin_amdgcn_s_sleep(1);
        }
      }
      const unsigned slot = (unsigned)(kt % NSLOT) * SLOT;
      const int koff = kt * BK;
      #pragma unroll
      for (int j = 0; j < 2; j++) gld_lds16(Ap[j] + koff, &As[slot + aBase[j]]);
      #pragma unroll
      for (int j = 0; j < 2; j++) gld_lds16(Bp[j] + koff, &Bs[slot + bBase[j]]);
      if (kt >= 1) {
        __builtin_amdgcn_s_waitcnt(0x0F74);       // vmcnt(4): kt-1 landed
        if (lane == 0)
          __hip_atomic_fetch_add(&prod_done, 1u, __ATOMIC_RELAXED,
                                 __HIP_MEMORY_SCOPE_WORKGROUP);
      }
    }
    __builtin_amdgcn_s_waitcnt(0x0F70);           // vmcnt(0): last stage
    if (lane == 0)
      __hip_atomic_fetch_add(&prod_done, 1u, __ATOMIC_RELAXED,
                             __HIP_MEMORY_SCOPE_WORKGROUP);
    return;
  }

  // ------------------------- CONSUMER (waves 0-3) -------------------------
  const int wr   = wv >> 1;        // 2x2 wave grid over the 128x128 tile
  const int wc   = wv & 1;
  const int lrow = lane & 15;      // fragment m / n index
  const int lkq  = lane >> 4;      // 16-B k-granule index (0..3)

  // Swizzled LDS short-offsets for the 4 A-frags / 4 B-frags (slot-relative).
  unsigned aOff[4], bOff[4];
  #pragma unroll
  for (int i = 0; i < 4; i++) {
    const int ra = wr * 64 + i * 16 + lrow;
    const int la = ra >> 1, ga = (ra & 1) * 4 + lkq;
    aOff[i] = (unsigned)(la * 64 + (ga ^ (la & 7)) * 8);
    const int rb = wc * 64 + i * 16 + lrow;
    const int lb = rb >> 1, gb = (rb & 1) * 4 + lkq;
    bOff[i] = (unsigned)(lb * 64 + (gb ^ (lb & 7)) * 8);
  }

  f32x4 acc[4][4] = {};
  unsigned ready = 0;

  #pragma unroll 1
  for (int kt = 0; kt < NK; kt++) {
    const unsigned need = 4u * (unsigned)(kt + 1);
    if (ready < need) {
      while (true) {
        ready = __hip_atomic_load(&prod_done, __ATOMIC_ACQUIRE,
                                  __HIP_MEMORY_SCOPE_WORKGROUP);
        if (ready >= need) break;
        __builtin_amdgcn_s_sleep(1);
      }
    }
    const unsigned cur = (unsigned)(kt % NSLOT) * SLOT;

    short8 af[4], bf[4];
    #pragma unroll
    for (int mi = 0; mi < 4; mi++)
      af[mi] = *reinterpret_cast<const short8*>(&As[cur + aOff[mi]]);
    #pragma unroll
    for (int ni = 0; ni < 4; ni++)
      bf[ni] = *reinterpret_cast<const short8*>(&Bs[cur + bOff[ni]]);

    #pragma unroll
    for (int mi = 0; mi < 4; mi++)
      #pragma unroll
      for (int ni = 0; ni < 4; ni++)
        acc[mi][ni] = __builtin_amdgcn_mfma_f32_16x16x32_bf16(
            af[mi], bf[ni], acc[mi][ni], 0, 0, 0);

    if (lane == 0)
      __hip_atomic_fetch_add(&cons_done, 1u, __ATOMIC_RELEASE,
                             __HIP_MEMORY_SCOPE_WORKGROUP);
  }

  // Epilogue: C/D layout col=lane&15, row=(lane>>4)*4+reg  [measured m89/m91]
  const int rbse = (lane >> 4) * 4;
  #pragma unroll
  for (int ni = 0; ni < 4; ni++) {
    const int col = n0 + wc * 64 + ni * 16 + lrow;
    const float bv = bias[col];
    #pragma unroll
    for (int mi = 0; mi < 4; mi++) {
      const int rowm = m0 + wr * 64 + mi * 16 + rbse;
      #pragma unroll
      for (int r = 0; r < 4; r++)
        out[(size_t)(rowm + r) * OUT_DIM + col] = acc[mi][ni][r] + bv;
    }
  }
}

// ---------------------------------------------------------------------------
extern "C" void kernel_launch(void* const* d_in, const int* in_sizes, int n_in,
                              void* d_out, int out_size, void* d_ws, size_t ws_size,
                              hipStream_t stream) {
  const float* x    = (const float*)d_in[0];
  const float* lnw  = (const float*)d_in[1];
  const float* lnb  = (const float*)d_in[2];
  const float* sw   = (const float*)d_in[3];   // (OUT, IN, 8)
  const float* sb   = (const float*)d_in[4];   // (OUT, IN)
  const float* bias = (const float*)d_in[5];   // (OUT,)
  const float* beta = (const float*)d_in[6];   // (1,)
  const float* grid = (const float*)d_in[7];   // (8,)
  float* out = (float*)d_out;

  unsigned short* A = (unsigned short*)d_ws;               // BATCH x KDIM bf16 (33.5 MB)
  unsigned short* B = A + (size_t)BATCH * KDIM;            // OUT   x KDIM bf16 (16.8 MB)

  hipLaunchKernelGGL(ln_rbf_kernel, dim3(BATCH), dim3(256), 0, stream,
                     x, lnw, lnb, beta, grid, A);
  hipLaunchKernelGGL(pack_b_kernel, dim3((SW_F4 + SB_F4) / 256), dim3(256), 0, stream,
                     sw, sb, (unsigned*)B);
  hipLaunchKernelGGL(gemm_kernel, dim3(OUT_DIM / TILE, BATCH / TILE), dim3(512), 0, stream,
                     A, B, bias, out);
}

// Round 6
// 304.399 us; speedup vs baseline: 1.0640x; 1.0640x over previous
//
#include <hip/hip_runtime.h>
#include <hip/hip_bf16.h>
#include <stdint.h>

// Problem constants
constexpr int IN_DIM   = 2048;
constexpr int OUT_DIM  = 2048;
constexpr int BATCH    = 4096;
constexpr int KDIM     = 2 * IN_DIM;   // concatenated K: [xn | S] vs [scale_base | Wd]
constexpr float LN_EPS = 1e-5f;

#define TILE 128
#define BK   64
constexpr int NK    = KDIM / BK;       // 64 k-steps
constexpr int STAGE = TILE * BK;       // shorts per matrix per stage (16 KB)

typedef __attribute__((ext_vector_type(8))) short  short8;  // 8 x bf16 (4 VGPRs)
typedef __attribute__((ext_vector_type(4))) float  f32x4;   // MFMA accumulator

__device__ __forceinline__ unsigned short f2bf(float f) {
  __hip_bfloat16 h = __float2bfloat16(f);
  return *reinterpret_cast<unsigned short*>(&h);
}
__device__ __forceinline__ unsigned pack2bf(float a, float b) {
  return (unsigned)f2bf(a) | ((unsigned)f2bf(b) << 16);
}

// ---------------------------------------------------------------------------
// Kernel 1 (FUSED prep): blocks [0, BATCH) do LayerNorm+RBF rows;
// blocks [BATCH, BATCH + (SW_F4+SB_F4)/256) do the B-pack.
// Branch is block-uniform; fusing removes one launch gap and lets the two
// phases' HBM traffic pipeline across the dispatch.
// ---------------------------------------------------------------------------
constexpr int SW_F4   = OUT_DIM * IN_DIM * 2;   // float4 count of spline_weight
constexpr int SB_F4   = OUT_DIM * IN_DIM / 4;   // float4 count of scale_base
constexpr int PACK_BLOCKS = (SW_F4 + SB_F4) / 256;

__global__ __launch_bounds__(256) void prep_kernel(
    const float* __restrict__ x, const float* __restrict__ lnw,
    const float* __restrict__ lnb, const float* __restrict__ betap,
    const float* __restrict__ grid, unsigned short* __restrict__ A,
    const float* __restrict__ sw, const float* __restrict__ sb,
    unsigned* __restrict__ Bu)    // B as uint (2 bf16 per uint), OUT x KDIM/2
{
  const int tid = threadIdx.x;
  if (blockIdx.x < BATCH) {
    // ----------------------- LayerNorm + RBF path -----------------------
    const int row = blockIdx.x;
    const float4* xr = reinterpret_cast<const float4*>(x + (size_t)row * IN_DIM);
    float4 v0 = xr[tid];
    float4 v1 = xr[tid + 256];
    float s = (v0.x + v0.y) + (v0.z + v0.w) + (v1.x + v1.y) + (v1.z + v1.w);
    float q = v0.x * v0.x + v0.y * v0.y + v0.z * v0.z + v0.w * v0.w
            + v1.x * v1.x + v1.y * v1.y + v1.z * v1.z + v1.w * v1.w;
    #pragma unroll
    for (int off = 32; off > 0; off >>= 1) {
      s += __shfl_down(s, off, 64);
      q += __shfl_down(q, off, 64);
    }
    __shared__ float red[10];
    const int lane = tid & 63, wv = tid >> 6;
    if (lane == 0) { red[wv] = s; red[4 + wv] = q; }
    __syncthreads();
    if (tid == 0) {
      float ts = (red[0] + red[1]) + (red[2] + red[3]);
      float tq = (red[4] + red[5]) + (red[6] + red[7]);
      float mu  = ts * (1.0f / IN_DIM);
      float var = tq * (1.0f / IN_DIM) - mu * mu;
      red[8] = mu;
      red[9] = rsqrtf(var + LN_EPS);
    }
    __syncthreads();
    const float mu = red[8], rs = red[9];
    const float beta = fminf(fmaxf(betap[0], 0.5f), 6.0f);
    float g[8];
    #pragma unroll
    for (int i = 0; i < 8; i++) g[i] = grid[i];
    const float4* w4 = reinterpret_cast<const float4*>(lnw);
    const float4* b4 = reinterpret_cast<const float4*>(lnb);
    unsigned short* Ar = A + (size_t)row * KDIM;
    #pragma unroll
    for (int h = 0; h < 2; h++) {
      const int idx = tid + h * 256;        // float4 index within the row
      float4 xv  = (h == 0) ? v0 : v1;
      float4 wv4 = w4[idx];
      float4 bv4 = b4[idx];
      float xa[4] = {xv.x, xv.y, xv.z, xv.w};
      float wa[4] = {wv4.x, wv4.y, wv4.z, wv4.w};
      float ba[4] = {bv4.x, bv4.y, bv4.z, bv4.w};
      float xn[4], S[4];
      #pragma unroll
      for (int c = 0; c < 4; c++) {
        float xnv = (xa[c] - mu) * rs * wa[c] + ba[c];
        xn[c] = xnv;
        float acc = 0.f;
        #pragma unroll
        for (int gg = 0; gg < 8; gg++) {
          float d = xnv - g[gg];
          acc += __expf(-beta * d * d);
        }
        S[c] = acc;
      }
      uint2 px, ps;
      px.x = pack2bf(xn[0], xn[1]);
      px.y = pack2bf(xn[2], xn[3]);
      ps.x = pack2bf(S[0], S[1]);
      ps.y = pack2bf(S[2], S[3]);
      *reinterpret_cast<uint2*>(Ar + idx * 4) = px;
      *reinterpret_cast<uint2*>(Ar + IN_DIM + idx * 4) = ps;
    }
  } else {
    // --------------------------- B-pack path ---------------------------
    const int g = (blockIdx.x - BATCH) * 256 + tid;
    const int lane = tid & 63;
    if (g < SW_F4) {
      float4 v = reinterpret_cast<const float4*>(sw)[g];
      float s = (v.x + v.y) + (v.z + v.w);
      s += __shfl_xor(s, 1, 64);               // full Wd[i] in both lanes of pair
      float hi = __shfl_down(s, 2, 64);        // Wd of i+1 for even-pair lanes
      if ((lane & 3) == 0) {
        const int i_lin = g >> 1;              // linear (o,i)
        const int o = i_lin >> 11;             // / IN_DIM
        const int i = i_lin & (IN_DIM - 1);
        Bu[(size_t)o * (KDIM / 2) + (IN_DIM / 2) + (i >> 1)] = pack2bf(s, hi);
      }
    } else {
      const int t = g - SW_F4;                 // [0, SB_F4)
      float4 v = reinterpret_cast<const float4*>(sb)[t];
      const int o  = t >> 9;                   // 512 float4 per sb row
      const int i4 = t & 511;
      uint2 u;
      u.x = pack2bf(v.x, v.y);
      u.y = pack2bf(v.z, v.w);
      *reinterpret_cast<uint2*>(&Bu[(size_t)o * (KDIM / 2) + i4 * 2]) = u;
    }
  }
}

// ---------------------------------------------------------------------------
// Kernel 2: C = A @ B^T + bias.  M=BATCH, N=OUT_DIM, K=KDIM, bf16 MFMA.
// R3 structure (best measured): 128x128 tile, BK=64, 256 thr / 4 waves
// (2x2 of 64x64), XOR-swizzled LDS, global_load_lds width=16, double-buffered
// stages, one barrier per k-step.
// NEW: XCD supertile swizzle. All 512 blocks are co-resident (2/CU); block d
// lands on XCD d%8 [m09]. Map d so each XCD's 64 blocks form an 8x8
// (bm,bn) square: per-XCD k-slice working set = 256 KB/stage (fits 4 MB L2),
// so A/B stage fetches hit L2 instead of re-filling from L3/HBM.
//   x = d&7 (square), q = d>>3:  bm = (x>>1)*8 + (q>>3), bn = (x&1)*8 + (q&7)
// ---------------------------------------------------------------------------
__device__ __forceinline__ void gld_lds16(const unsigned short* g, unsigned short* l) {
  __builtin_amdgcn_global_load_lds(
      (const __attribute__((address_space(1))) void*)g,
      (__attribute__((address_space(3))) void*)l, 16, 0, 0);
}

__global__ __launch_bounds__(256) void gemm_kernel(
    const unsigned short* __restrict__ A, const unsigned short* __restrict__ Bm,
    const float* __restrict__ bias, float* __restrict__ out)
{
  __shared__ __align__(16) unsigned short As[2 * STAGE];   // 32 KB
  __shared__ __align__(16) unsigned short Bs[2 * STAGE];   // 32 KB
  const int tid  = threadIdx.x;
  const int lane = tid & 63;
  const int wv   = tid >> 6;
  const int wr   = wv >> 1;        // 2x2 wave grid over the 128x128 tile
  const int wc   = wv & 1;
  // XCD supertile swizzle
  const int gid = blockIdx.x;
  const int sq  = gid & 7;
  const int q   = gid >> 3;
  const int m0  = ((sq >> 1) * 8 + (q >> 3)) * TILE;   // bm in [0,32)
  const int n0  = ((sq & 1) * 8 + (q & 7)) * TILE;     // bn in [0,16)
  const int lrow = lane & 15;      // fragment m / n index
  const int lkq  = lane >> 4;      // k-quarter within a 16-B-granule row

  f32x4 acc[4][4] = {};

  // Staging: 1024 16-B segments per matrix per stage; seg s -> LDS slot s;
  // slot (row = s>>3, col8' = s&7) holds global col8 = col8' ^ (row&7)
  // (swizzle folded into the GLOBAL fetch address; LDS dest is wave-uniform
  // base + lane*16 [m104/m108]).
  const unsigned short* Ap[4];
  const unsigned short* Bp[4];
  unsigned short* ldsA[4];
  unsigned short* ldsB[4];
  #pragma unroll
  for (int j = 0; j < 4; j++) {
    const int seg  = j * 256 + wv * 64 + lane;
    const int row  = seg >> 3;
    const int gcol = ((seg & 7) ^ (row & 7)) * 8;
    Ap[j] = A  + (size_t)(m0 + row) * KDIM + gcol;
    Bp[j] = Bm + (size_t)(n0 + row) * KDIM + gcol;
    ldsA[j] = &As[(j * 256 + wv * 64) * 8];
    ldsB[j] = &Bs[(j * 256 + wv * 64) * 8];
  }

  // Prologue: stage 0 into buffer 0.
  #pragma unroll
  for (int j = 0; j < 4; j++) gld_lds16(Ap[j], ldsA[j]);
  #pragma unroll
  for (int j = 0; j < 4; j++) gld_lds16(Bp[j], ldsB[j]);

  #pragma unroll 1
  for (int kt = 0; kt < NK; kt++) {
    __syncthreads();               // drains stage-kt loads (issued a stage ago)
    const int cur = (kt & 1) * STAGE;
    if (kt + 1 < NK) {             // wave-uniform; prefetch stage kt+1
      const int nxt = ((kt + 1) & 1) * STAGE;
      const int koff = (kt + 1) * BK;
      #pragma unroll
      for (int j = 0; j < 4; j++) gld_lds16(Ap[j] + koff, ldsA[j] + nxt);
      #pragma unroll
      for (int j = 0; j < 4; j++) gld_lds16(Bp[j] + koff, ldsB[j] + nxt);
    }

    short8 af[2][4], bf[2][4];
    #pragma unroll
    for (int h = 0; h < 2; h++) {
      #pragma unroll
      for (int mi = 0; mi < 4; mi++) {
        const int r = wr * 64 + mi * 16 + lrow;
        af[h][mi] = *reinterpret_cast<const short8*>(
            &As[cur + r * BK + (((h << 2) | lkq) ^ (lrow & 7)) * 8]);
      }
      #pragma unroll
      for (int ni = 0; ni < 4; ni++) {
        const int r = wc * 64 + ni * 16 + lrow;
        bf[h][ni] = *reinterpret_cast<const short8*>(
            &Bs[cur + r * BK + (((h << 2) | lkq) ^ (lrow & 7)) * 8]);
      }
    }
    #pragma unroll
    for (int h = 0; h < 2; h++)
      #pragma unroll
      for (int mi = 0; mi < 4; mi++)
        #pragma unroll
        for (int ni = 0; ni < 4; ni++)
          acc[mi][ni] = __builtin_amdgcn_mfma_f32_16x16x32_bf16(
              af[h][mi], bf[h][ni], acc[mi][ni], 0, 0, 0);
  }

  // Epilogue: C/D layout col=lane&15, row=(lane>>4)*4+reg  [measured m89/m91]
  const int rb = (lane >> 4) * 4;
  #pragma unroll
  for (int ni = 0; ni < 4; ni++) {
    const int col = n0 + wc * 64 + ni * 16 + lrow;
    const float bv = bias[col];
    #pragma unroll
    for (int mi = 0; mi < 4; mi++) {
      const int rowm = m0 + wr * 64 + mi * 16 + rb;
      #pragma unroll
      for (int r = 0; r < 4; r++)
        out[(size_t)(rowm + r) * OUT_DIM + col] = acc[mi][ni][r] + bv;
    }
  }
}

// ---------------------------------------------------------------------------
extern "C" void kernel_launch(void* const* d_in, const int* in_sizes, int n_in,
                              void* d_out, int out_size, void* d_ws, size_t ws_size,
                              hipStream_t stream) {
  const float* x    = (const float*)d_in[0];
  const float* lnw  = (const float*)d_in[1];
  const float* lnb  = (const float*)d_in[2];
  const float* sw   = (const float*)d_in[3];   // (OUT, IN, 8)
  const float* sb   = (const float*)d_in[4];   // (OUT, IN)
  const float* bias = (const float*)d_in[5];   // (OUT,)
  const float* beta = (const float*)d_in[6];   // (1,)
  const float* grid = (const float*)d_in[7];   // (8,)
  float* out = (float*)d_out;

  unsigned short* A = (unsigned short*)d_ws;               // BATCH x KDIM bf16 (33.5 MB)
  unsigned short* B = A + (size_t)BATCH * KDIM;            // OUT   x KDIM bf16 (16.8 MB)

  hipLaunchKernelGGL(prep_kernel, dim3(BATCH + PACK_BLOCKS), dim3(256), 0, stream,
                     x, lnw, lnb, beta, grid, A, sw, sb, (unsigned*)B);
  hipLaunchKernelGGL(gemm_kernel, dim3((BATCH / TILE) * (OUT_DIM / TILE)), dim3(256), 0, stream,
                     A, B, bias, out);
}